// Round 1
// baseline (396.050 us; speedup 1.0000x reference)
//
#include <hip/hip_runtime.h>
#include <math.h>

#define B 32
#define C 512
#define H 56
#define W 56
#define HW (H * W)      // 3136
#define HW4 (HW / 4)    // 784
#define KD 768

// ---------------- Kernel 1: channel-wise max + mean pooling ----------------
// Block: 256 threads = 64 float4-positions x 4 channel-groups.
// Each thread reduces 128 channels for its 4 hw positions; LDS-reduce across
// the 4 channel groups. Coalesced: lanes 0..63 read consecutive float4s (1 KiB/instr).
__global__ __launch_bounds__(256) void pool_kernel(
    const float* __restrict__ x, float* __restrict__ cmax, float* __restrict__ cmean) {
    const int tid  = threadIdx.x;
    const int lane = tid & 63;
    const int cg   = tid >> 6;                    // 0..3
    const int p    = blockIdx.x * 64 + lane;      // float4 position in [0, B*HW4)
    const int b    = p / HW4;
    const int hw4  = p - b * HW4;

    const float4* xb = (const float4*)x + (size_t)b * C * HW4 + hw4;

    float4 mx = make_float4(-INFINITY, -INFINITY, -INFINITY, -INFINITY);
    float4 sm = make_float4(0.f, 0.f, 0.f, 0.f);
    const int c0 = cg * (C / 4);
    #pragma unroll 4
    for (int c = c0; c < c0 + C / 4; ++c) {
        float4 v = xb[(size_t)c * HW4];
        mx.x = fmaxf(mx.x, v.x); mx.y = fmaxf(mx.y, v.y);
        mx.z = fmaxf(mx.z, v.z); mx.w = fmaxf(mx.w, v.w);
        sm.x += v.x; sm.y += v.y; sm.z += v.z; sm.w += v.w;
    }

    __shared__ float4 smax[4][64];
    __shared__ float4 ssum[4][64];
    smax[cg][lane] = mx;
    ssum[cg][lane] = sm;
    __syncthreads();

    if (cg == 0) {
        #pragma unroll
        for (int g = 1; g < 4; ++g) {
            float4 m2 = smax[g][lane];
            float4 s2 = ssum[g][lane];
            mx.x = fmaxf(mx.x, m2.x); mx.y = fmaxf(mx.y, m2.y);
            mx.z = fmaxf(mx.z, m2.z); mx.w = fmaxf(mx.w, m2.w);
            sm.x += s2.x; sm.y += s2.y; sm.z += s2.z; sm.w += s2.w;
        }
        const float inv = 1.0f / (float)C;
        float4 mn = make_float4(sm.x * inv, sm.y * inv, sm.z * inv, sm.w * inv);
        ((float4*)cmax)[p]  = mx;
        ((float4*)cmean)[p] = mn;
    }
}

// ---------------- Kernel 2: keyword bias (Linear KD->1) per batch ----------------
__global__ __launch_bounds__(256) void bias_kernel(
    const float* __restrict__ keyword, const float* __restrict__ proj_w,
    const float* __restrict__ proj_b, float* __restrict__ bias) {
    const int b   = blockIdx.x;
    const int tid = threadIdx.x;
    float s = 0.f;
    for (int k = tid; k < KD; k += 256)
        s += keyword[b * KD + k] * proj_w[k];
    #pragma unroll
    for (int off = 32; off > 0; off >>= 1)
        s += __shfl_down(s, off);
    __shared__ float warp_s[4];
    if ((tid & 63) == 0) warp_s[tid >> 6] = s;
    __syncthreads();
    if (tid == 0)
        bias[b] = warp_s[0] + warp_s[1] + warp_s[2] + warp_s[3] + proj_b[0];
}

// ---------------- Kernel 3: 7x7 conv (2ch->1) + bias + sigmoid -> scale ----------------
__global__ __launch_bounds__(256) void conv_kernel(
    const float* __restrict__ cmax, const float* __restrict__ cmean,
    const float* __restrict__ conv_w, const float* __restrict__ conv_b,
    const float* __restrict__ bias, float* __restrict__ scale) {
    __shared__ float wsm[98];   // [0..48] = max-channel weights, [49..97] = mean-channel
    __shared__ float cb;
    const int tid = threadIdx.x;
    if (tid < 98) wsm[tid] = conv_w[tid];
    if (tid == 98) cb = conv_b[0];
    __syncthreads();

    const int o  = blockIdx.x * 256 + tid;   // [0, B*HW)
    const int b  = o / HW;
    const int hw = o - b * HW;
    const int h  = hw / W;
    const int w  = hw - h * W;

    float acc = cb + bias[b];
    const float* cmx = cmax  + b * HW;
    const float* cmn = cmean + b * HW;
    #pragma unroll
    for (int kh = 0; kh < 7; ++kh) {
        const int ih = h + kh - 3;
        if (ih < 0 || ih >= H) continue;
        #pragma unroll
        for (int kw = 0; kw < 7; ++kw) {
            const int iw = w + kw - 3;
            if (iw < 0 || iw >= W) continue;
            const int idx = ih * W + iw;
            acc = fmaf(cmx[idx], wsm[kh * 7 + kw],
                  fmaf(cmn[idx], wsm[49 + kh * 7 + kw], acc));
        }
    }
    scale[o] = 1.0f / (1.0f + __expf(-acc));
}

// ---------------- Kernel 4: out = x * scale (broadcast over C) ----------------
__global__ __launch_bounds__(256) void scale_kernel(
    const float4* __restrict__ x4, const float4* __restrict__ scale4,
    float4* __restrict__ out4) {
    const int v    = blockIdx.x * 256 + threadIdx.x;   // float4 index, [0, B*C*HW4)
    const int rowv = v / HW4;        // b*C + c
    const int hwv  = v - rowv * HW4;
    const int b    = rowv >> 9;      // / C
    float4 xv = x4[v];
    float4 sv = scale4[b * HW4 + hwv];
    out4[v] = make_float4(xv.x * sv.x, xv.y * sv.y, xv.z * sv.z, xv.w * sv.w);
}

extern "C" void kernel_launch(void* const* d_in, const int* in_sizes, int n_in,
                              void* d_out, int out_size, void* d_ws, size_t ws_size,
                              hipStream_t stream) {
    const float* x       = (const float*)d_in[0];
    const float* keyword = (const float*)d_in[1];
    const float* conv_w  = (const float*)d_in[2];
    const float* conv_b  = (const float*)d_in[3];
    const float* proj_w  = (const float*)d_in[4];
    const float* proj_b  = (const float*)d_in[5];
    float* out = (float*)d_out;

    float* ws    = (float*)d_ws;
    float* cmax  = ws;                 // B*HW floats
    float* cmean = ws + B * HW;        // B*HW floats
    float* scale = ws + 2 * B * HW;    // B*HW floats
    float* bias  = ws + 3 * B * HW;    // B floats

    // 1) pooling: B*HW4 / 64 positions per block
    pool_kernel<<<(B * HW4) / 64, 256, 0, stream>>>(x, cmax, cmean);
    // 2) keyword bias
    bias_kernel<<<B, 256, 0, stream>>>(keyword, proj_w, proj_b, bias);
    // 3) conv + sigmoid
    conv_kernel<<<(B * HW) / 256, 256, 0, stream>>>(cmax, cmean, conv_w, conv_b, bias, scale);
    // 4) elementwise scale
    scale_kernel<<<(B * C * HW4) / 256, 256, 0, stream>>>(
        (const float4*)x, (const float4*)scale, (float4*)out);
}

// Round 3
// 391.411 us; speedup vs baseline: 1.0119x; 1.0119x over previous
//
#include <hip/hip_runtime.h>
#include <math.h>

#define B 32
#define C 512
#define H 56
#define W 56
#define HW (H * W)      // 3136
#define HW4 (HW / 4)    // 784
#define KD 768

typedef float floatx4 __attribute__((ext_vector_type(4)));   // native vector: NT-builtin-compatible

// ---------------- Kernel 1: channel-wise max + mean pooling ----------------
// Block: 512 threads = 32 float4-positions x 16 channel-groups (32 ch each).
// Grid 784 blocks -> ~24 waves/CU for latency hiding. Each wave's load = two
// 512B contiguous segments (32 consecutive float4 at each of 2 channels).
__global__ __launch_bounds__(512) void pool_kernel(
    const float* __restrict__ x, float* __restrict__ cmax, float* __restrict__ cmean) {
    const int tid = threadIdx.x;
    const int pos = tid & 31;          // 0..31
    const int cg  = tid >> 5;          // 0..15
    const int p   = blockIdx.x * 32 + pos;   // float4 position in [0, B*HW4)
    const int b   = p / HW4;
    const int hw4 = p - b * HW4;

    const floatx4* xb = (const floatx4*)x + (size_t)b * C * HW4 + hw4;

    floatx4 mx = { -INFINITY, -INFINITY, -INFINITY, -INFINITY };
    floatx4 sm = { 0.f, 0.f, 0.f, 0.f };
    const int c0 = cg * 32;
    #pragma unroll 4
    for (int c = c0; c < c0 + 32; ++c) {
        floatx4 v = xb[(size_t)c * HW4];
        mx.x = fmaxf(mx.x, v.x); mx.y = fmaxf(mx.y, v.y);
        mx.z = fmaxf(mx.z, v.z); mx.w = fmaxf(mx.w, v.w);
        sm += v;
    }

    __shared__ floatx4 smax[16][32];
    __shared__ floatx4 ssum[16][32];
    smax[cg][pos] = mx;
    ssum[cg][pos] = sm;
    __syncthreads();

    if (tid < 32) {
        mx = smax[0][tid];
        sm = ssum[0][tid];
        #pragma unroll
        for (int g = 1; g < 16; ++g) {
            floatx4 m2 = smax[g][tid];
            mx.x = fmaxf(mx.x, m2.x); mx.y = fmaxf(mx.y, m2.y);
            mx.z = fmaxf(mx.z, m2.z); mx.w = fmaxf(mx.w, m2.w);
            sm += ssum[g][tid];
        }
        const float inv = 1.0f / (float)C;
        floatx4 mn = sm * inv;
        const int pp = blockIdx.x * 32 + tid;
        ((floatx4*)cmax)[pp]  = mx;
        ((floatx4*)cmean)[pp] = mn;
    }
}

// ---------------- Kernel 2: keyword bias (Linear KD->1) per batch ----------------
__global__ __launch_bounds__(256) void bias_kernel(
    const float* __restrict__ keyword, const float* __restrict__ proj_w,
    const float* __restrict__ proj_b, float* __restrict__ bias) {
    const int b   = blockIdx.x;
    const int tid = threadIdx.x;
    float s = 0.f;
    for (int k = tid; k < KD; k += 256)
        s += keyword[b * KD + k] * proj_w[k];
    #pragma unroll
    for (int off = 32; off > 0; off >>= 1)
        s += __shfl_down(s, off);
    __shared__ float warp_s[4];
    if ((tid & 63) == 0) warp_s[tid >> 6] = s;
    __syncthreads();
    if (tid == 0)
        bias[b] = warp_s[0] + warp_s[1] + warp_s[2] + warp_s[3] + proj_b[0];
}

// ---------------- Kernel 3: 7x7 conv (2ch->1) + bias + sigmoid -> scale ----------------
__global__ __launch_bounds__(256) void conv_kernel(
    const float* __restrict__ cmax, const float* __restrict__ cmean,
    const float* __restrict__ conv_w, const float* __restrict__ conv_b,
    const float* __restrict__ bias, float* __restrict__ scale) {
    __shared__ float wsm[98];   // [0..48] = max-channel weights, [49..97] = mean-channel
    __shared__ float cb;
    const int tid = threadIdx.x;
    if (tid < 98) wsm[tid] = conv_w[tid];
    if (tid == 98) cb = conv_b[0];
    __syncthreads();

    const int o  = blockIdx.x * 256 + tid;   // [0, B*HW)
    const int b  = o / HW;
    const int hw = o - b * HW;
    const int h  = hw / W;
    const int w  = hw - h * W;

    float acc = cb + bias[b];
    const float* cmx = cmax  + b * HW;
    const float* cmn = cmean + b * HW;
    #pragma unroll
    for (int kh = 0; kh < 7; ++kh) {
        const int ih = h + kh - 3;
        if (ih < 0 || ih >= H) continue;
        #pragma unroll
        for (int kw = 0; kw < 7; ++kw) {
            const int iw = w + kw - 3;
            if (iw < 0 || iw >= W) continue;
            const int idx = ih * W + iw;
            acc = fmaf(cmx[idx], wsm[kh * 7 + kw],
                  fmaf(cmn[idx], wsm[49 + kh * 7 + kw], acc));
        }
    }
    scale[o] = 1.0f / (1.0f + __expf(-acc));
}

// ---------------- Kernel 4: out = x * scale (broadcast over C) ----------------
// 4 float4/thread, block-strided (coalesced). NT loads for x (last use, keep
// L3 copy intact), NT stores for out (stream past caches).
__global__ __launch_bounds__(256) void scale_kernel(
    const floatx4* __restrict__ x4, const floatx4* __restrict__ scale4,
    floatx4* __restrict__ out4) {
    const int base = blockIdx.x * 1024 + threadIdx.x;
    #pragma unroll
    for (int k = 0; k < 4; ++k) {
        const int v    = base + k * 256;          // float4 index
        const int rowv = v / HW4;                 // b*C + c
        const int hwv  = v - rowv * HW4;
        const int b    = rowv >> 9;               // / C
        floatx4 xv = __builtin_nontemporal_load(&x4[v]);
        floatx4 sv = scale4[b * HW4 + hwv];
        floatx4 o  = xv * sv;
        __builtin_nontemporal_store(o, &out4[v]);
    }
}

extern "C" void kernel_launch(void* const* d_in, const int* in_sizes, int n_in,
                              void* d_out, int out_size, void* d_ws, size_t ws_size,
                              hipStream_t stream) {
    const float* x       = (const float*)d_in[0];
    const float* keyword = (const float*)d_in[1];
    const float* conv_w  = (const float*)d_in[2];
    const float* conv_b  = (const float*)d_in[3];
    const float* proj_w  = (const float*)d_in[4];
    const float* proj_b  = (const float*)d_in[5];
    float* out = (float*)d_out;

    float* ws    = (float*)d_ws;
    float* cmax  = ws;                 // B*HW floats
    float* cmean = ws + B * HW;        // B*HW floats
    float* scale = ws + 2 * B * HW;    // B*HW floats
    float* bias  = ws + 3 * B * HW;    // B floats

    // bias first (independent, tiny) so it never sits between the big kernels
    bias_kernel<<<B, 256, 0, stream>>>(keyword, proj_w, proj_b, bias);
    // 1) pooling: 32 float4 positions per block, 16 channel groups
    pool_kernel<<<(B * HW4) / 32, 512, 0, stream>>>(x, cmax, cmean);
    // 2) conv + sigmoid
    conv_kernel<<<(B * HW) / 256, 256, 0, stream>>>(cmax, cmean, conv_w, conv_b, bias, scale);
    // 3) elementwise scale
    scale_kernel<<<(B * C * HW4) / 1024, 256, 0, stream>>>(
        (const floatx4*)x, (const floatx4*)scale, (float4*)out ? (floatx4*)out : (floatx4*)out);
}